// Round 1
// 320.072 us; speedup vs baseline: 1.2285x; 1.2285x over previous
//
#include <hip/hip_runtime.h>

#define NB 262144
#define AA 10
#define DD 10
#define KK 32

typedef float v2f __attribute__((ext_vector_type(2)));

// ---- bf16 helpers -----------------------------------------------------------
static __device__ __forceinline__ float b2f(unsigned short h) {
    union { unsigned u; float f; } c; c.u = ((unsigned)h) << 16; return c.f;
}
static __device__ __forceinline__ float bflo(unsigned w) {
    union { unsigned u; float f; } c; c.u = w << 16; return c.f;
}
static __device__ __forceinline__ float bfhi(unsigned w) {
    union { unsigned u; float f; } c; c.u = w & 0xffff0000u; return c.f;
}
static __device__ __forceinline__ v2f mk2(float a, float b) {
    v2f r; r.x = a; r.y = b; return r;
}

// f32-vs-bf16 detection by exponent-field statistics (verified in prior session).
__device__ __forceinline__ int detect_f32(const unsigned short* p, int nshorts,
                                          unsigned expthr, int lane) {
    int bad = 0;
    if (lane < nshorts) {
        unsigned e = (p[lane] >> 7) & 0xFFu;
        bad = (e >= expthr);
    }
    return __any(bad);
}

// ---- prep: convert all weights to f32 into workspace ------------------------
// wf layout: [0:100) M  [100:420) Pu  [420:452) pu  [452:772) Pi  [772:804) pi
__global__ __launch_bounds__(64) void prep_weights(
    const unsigned short* __restrict__ wM,
    const unsigned short* __restrict__ wPu,
    const unsigned short* __restrict__ wpu,
    const unsigned short* __restrict__ wPi,
    const unsigned short* __restrict__ wpi,
    float* __restrict__ wf)
{
    const int t = threadIdx.x;
    int f = 0;
    f |= detect_f32(wM,  64, 125, t) << 0;
    f |= detect_f32(wPu, 64, 125, t) << 1;
    f |= detect_f32(wpu, 32, 125, t) << 2;
    f |= detect_f32(wPi, 64, 125, t) << 3;
    f |= detect_f32(wpi, 32, 125, t) << 4;
    const float* fM  = (const float*)wM;
    const float* fPu = (const float*)wPu;
    const float* fpu = (const float*)wpu;
    const float* fPi = (const float*)wPi;
    const float* fpi = (const float*)wpi;
    for (int i = t; i < 100; i += 64) wf[i]       = (f & 1)  ? fM[i]  : b2f(wM[i]);
    for (int i = t; i < 320; i += 64) wf[100 + i] = (f & 2)  ? fPu[i] : b2f(wPu[i]);
    if (t < 32)                       wf[420 + t] = (f & 4)  ? fpu[t] : b2f(wpu[t]);
    for (int i = t; i < 320; i += 64) wf[452 + i] = (f & 8)  ? fPi[i] : b2f(wPi[i]);
    if (t < 32)                       wf[772 + t] = (f & 16) ? fpi[t] : b2f(wpi[t]);
}

// ---- main kernel -------------------------------------------------------------
// One thread per batch. U,V live in registers as 50 float2-pairs each.
// Streaming schedule (no W/X arrays, no spills):
//   user pass, per u: um = U[u]·M (10f); Wrow = sum_v relu(um·V[v]) V[v] (10f);
//                     score += pu[k]*relu(Pu[k]·U[u] + Pi[k]·Wrow)
//   item pass, per v: mv = M·V[v] (10f);  Xrow = sum_u relu(U[u]·mv) U[u] (10f);
//                     score += pi[k]*relu(Pi[k]·V[v] + Pu[k]·Xrow)
// Weights read with uniform indices from wf -> SMEM s_load (scalar pipe).
// Inputs loaded directly per-thread (400 B/batch, 16B-aligned) - no LDS staging.
__global__ __launch_bounds__(64, 2) void aie_main(
    const unsigned short* __restrict__ user_rep,
    const unsigned short* __restrict__ item_rep,
    const float* __restrict__ wf,
    float* __restrict__ out)
{
    __shared__ float obuf[1408];   // 5.6 KB: raw scores then normalized outputs
    const int t = threadIdx.x;
    const long long b = (long long)blockIdx.x * 64 + t;

    const int fu = detect_f32(user_rep, 64, 137, t);
    const int fi = detect_f32(item_rep, 64, 137, t);

    v2f U2[AA][5], V2[AA][5];

    // ---- direct loads: item_rep -> V2 ----
    if (fi) {
        const float4* g = (const float4*)((const float*)item_rep + b * 100);
        #pragma unroll
        for (int j = 0; j < 25; j++) {
            float4 w = g[j];
            int p = 2 * j;
            V2[p / 5][p % 5]             = mk2(w.x, w.y);
            V2[(p + 1) / 5][(p + 1) % 5] = mk2(w.z, w.w);
        }
    } else {
        const uint2* g = (const uint2*)(item_rep + b * 100);
        #pragma unroll
        for (int j = 0; j < 25; j++) {
            uint2 w = g[j];
            int p = 2 * j;
            V2[p / 5][p % 5]             = mk2(bflo(w.x), bfhi(w.x));
            V2[(p + 1) / 5][(p + 1) % 5] = mk2(bflo(w.y), bfhi(w.y));
        }
    }
    // ---- direct loads: user_rep -> U2 ----
    if (fu) {
        const float4* g = (const float4*)((const float*)user_rep + b * 100);
        #pragma unroll
        for (int j = 0; j < 25; j++) {
            float4 w = g[j];
            int p = 2 * j;
            U2[p / 5][p % 5]             = mk2(w.x, w.y);
            U2[(p + 1) / 5][(p + 1) % 5] = mk2(w.z, w.w);
        }
    } else {
        const uint2* g = (const uint2*)(user_rep + b * 100);
        #pragma unroll
        for (int j = 0; j < 25; j++) {
            uint2 w = g[j];
            int p = 2 * j;
            U2[p / 5][p % 5]             = mk2(bflo(w.x), bfhi(w.x));
            U2[(p + 1) / 5][(p + 1) % 5] = mk2(bflo(w.y), bfhi(w.y));
        }
    }

    const v2f*  M2  = (const v2f*)wf;            // M2[d*5+j]  = M[d][2j,2j+1]
    const v2f*  Pu2 = (const v2f*)(wf + 100);    // Pu2[k*5+j]
    const float* pu = wf + 420;
    const v2f*  Pi2 = (const v2f*)(wf + 452);
    const float* pi = wf + 772;

    // =================== user branch ===================
    #pragma unroll
    for (int u = 0; u < AA; u++) {
        // um = U[u] · M   (row-vector times matrix), kept as 5 pairs over e
        v2f um2[5];
        {
            const float x0 = U2[u][0].x;
            #pragma unroll
            for (int j = 0; j < 5; j++) um2[j] = x0 * M2[j];
        }
        #pragma unroll
        for (int d = 1; d < DD; d++) {
            const float x = (d & 1) ? U2[u][d >> 1].y : U2[u][d >> 1].x;
            #pragma unroll
            for (int j = 0; j < 5; j++) um2[j] += x * M2[d * 5 + j];
        }
        // Wrow = sum_v relu(um·V[v]) * V[v]
        v2f Wr2[5];
        #pragma unroll
        for (int j = 0; j < 5; j++) Wr2[j] = mk2(0.f, 0.f);
        #pragma unroll
        for (int v = 0; v < AA; v++) {
            v2f r2 = um2[0] * V2[v][0];
            #pragma unroll
            for (int j = 1; j < 5; j++) r2 += um2[j] * V2[v][j];
            const float r = fmaxf(r2.x + r2.y, 0.f);
            #pragma unroll
            for (int j = 0; j < 5; j++) Wr2[j] += r * V2[v][j];
        }
        // k-loop: weights via uniform (scalar) loads
        float acc = 0.f;
        #pragma unroll 1
        for (int k0 = 0; k0 < KK; k0 += 8) {
            #pragma unroll
            for (int kk = 0; kk < 8; kk++) {
                const int k = k0 + kk;
                v2f a2 = Pu2[k * 5] * U2[u][0];
                v2f c2 = Pi2[k * 5] * Wr2[0];
                #pragma unroll
                for (int j = 1; j < 5; j++) {
                    a2 += Pu2[k * 5 + j] * U2[u][j];
                    c2 += Pi2[k * 5 + j] * Wr2[j];
                }
                const v2f s2 = a2 + c2;
                acc += pu[k] * fmaxf(s2.x + s2.y, 0.f);
            }
        }
        obuf[11 * t + u] = acc;
    }

    // =================== item branch ===================
    #pragma unroll
    for (int v = 0; v < AA; v++) {
        // mv[d] = M[d]·V[v]  (kept as 5 pairs over d)
        v2f mv2[5];
        #pragma unroll
        for (int dp = 0; dp < 5; dp++) {
            v2f s0 = M2[(2 * dp) * 5]     * V2[v][0];
            v2f s1 = M2[(2 * dp + 1) * 5] * V2[v][0];
            #pragma unroll
            for (int j = 1; j < 5; j++) {
                s0 += M2[(2 * dp) * 5 + j]     * V2[v][j];
                s1 += M2[(2 * dp + 1) * 5 + j] * V2[v][j];
            }
            mv2[dp] = mk2(s0.x + s0.y, s1.x + s1.y);
        }
        // Xrow = sum_u relu(U[u]·mv) * U[u]
        v2f Xr2[5];
        #pragma unroll
        for (int j = 0; j < 5; j++) Xr2[j] = mk2(0.f, 0.f);
        #pragma unroll
        for (int u = 0; u < AA; u++) {
            v2f r2 = mv2[0] * U2[u][0];
            #pragma unroll
            for (int j = 1; j < 5; j++) r2 += mv2[j] * U2[u][j];
            const float r = fmaxf(r2.x + r2.y, 0.f);
            #pragma unroll
            for (int j = 0; j < 5; j++) Xr2[j] += r * U2[u][j];
        }
        // k-loop
        float acc = 0.f;
        #pragma unroll 1
        for (int k0 = 0; k0 < KK; k0 += 8) {
            #pragma unroll
            for (int kk = 0; kk < 8; kk++) {
                const int k = k0 + kk;
                v2f a2 = Pi2[k * 5] * V2[v][0];
                v2f c2 = Pu2[k * 5] * Xr2[0];
                #pragma unroll
                for (int j = 1; j < 5; j++) {
                    a2 += Pi2[k * 5 + j] * V2[v][j];
                    c2 += Pu2[k * 5 + j] * Xr2[j];
                }
                const v2f s2 = a2 + c2;
                acc += pi[k] * fmaxf(s2.x + s2.y, 0.f);
            }
        }
        obuf[704 + 11 * t + v] = acc;
    }

    // ---- softmax both branches (thread-local, via LDS round-trip) ----
    #pragma unroll
    for (int h = 0; h < 2; h++) {
        const int base = 704 * h + 11 * t;
        float s[AA];
        #pragma unroll
        for (int u = 0; u < AA; u++) s[u] = obuf[base + u];
        float mx = s[0];
        #pragma unroll
        for (int u = 1; u < AA; u++) mx = fmaxf(mx, s[u]);
        float sum = 0.f;
        #pragma unroll
        for (int u = 0; u < AA; u++) { s[u] = __expf(s[u] - mx); sum += s[u]; }
        const float inv = 1.f / sum;
        #pragma unroll
        for (int u = 0; u < AA; u++) obuf[base + u] = s[u] * inv;
    }
    __syncthreads();

    // ---- coalesced output stores (float2 streams) ----
    {
        float2* o0 = (float2*)(out + (size_t)blockIdx.x * 640);
        float2* o1 = (float2*)(out + (size_t)NB * 10 + (size_t)blockIdx.x * 640);
        #pragma unroll
        for (int j = 0; j < 5; j++) {
            int m = t + 64 * j;
            int i = m / 5;
            int u = 2 * (m - 5 * i);
            o0[m] = make_float2(obuf[11 * i + u],       obuf[11 * i + u + 1]);
            o1[m] = make_float2(obuf[704 + 11 * i + u], obuf[704 + 11 * i + u + 1]);
        }
    }
}

extern "C" void kernel_launch(void* const* d_in, const int* in_sizes, int n_in,
                              void* d_out, int out_size, void* d_ws, size_t ws_size,
                              hipStream_t stream) {
    const unsigned short* user_rep = (const unsigned short*)d_in[0];
    const unsigned short* item_rep = (const unsigned short*)d_in[1];
    float* wf = (float*)d_ws;

    hipLaunchKernelGGL(prep_weights, dim3(1), dim3(64), 0, stream,
                       (const unsigned short*)d_in[2], (const unsigned short*)d_in[3],
                       (const unsigned short*)d_in[4], (const unsigned short*)d_in[5],
                       (const unsigned short*)d_in[6], wf);

    hipLaunchKernelGGL(aie_main, dim3(NB / 64), dim3(64), 0, stream,
                       user_rep, item_rep, wf, (float*)d_out);
}